// Round 1
// baseline (375.423 us; speedup 1.0000x reference)
//
#include <hip/hip_runtime.h>
#include <stdint.h>

#define N_NODES 50000
#define N_EDGES 600000
#define DIM     128
#define N_GRAPHS 512

typedef __attribute__((ext_vector_type(8))) short bf16x8;
typedef __attribute__((ext_vector_type(4))) float f32x4;

__device__ __forceinline__ short f2bf(float f) {
    union { float f; uint32_t u; } c; c.f = f;
    uint32_t u = c.u;
    u += 0x7fffu + ((u >> 16) & 1u);   // round-to-nearest-even
    return (short)(u >> 16);
}

// ---- pack a 128x128 f32 row-major W into bf16 B-fragment order ----
// frag idx = (ntile*4 + kstep)*64 + lane ; element j = W[k0+j][col]
// col = ntile*16 + (lane&15), k0 = kstep*32 + (lane>>4)*8
__global__ void pack_w_kernel(const float* __restrict__ W, short* __restrict__ Wp) {
    int idx = blockIdx.x * blockDim.x + threadIdx.x;
    if (idx >= 2048) return;
    int lane = idx & 63;
    int ks = (idx >> 6) & 3;
    int nt = idx >> 8;
    int col = nt * 16 + (lane & 15);
    int k0 = ks * 32 + ((lane >> 4) << 3);
    short* dst = Wp + idx * 8;
#pragma unroll
    for (int j = 0; j < 8; ++j) dst[j] = f2bf(W[(k0 + j) * DIM + col]);
}

__global__ void count_kernel(const int* __restrict__ ei, int* __restrict__ cnt) {
    int e = blockIdx.x * blockDim.x + threadIdx.x;
    if (e < N_EDGES) atomicAdd(&cnt[ei[N_EDGES + e]], 1);
}

// single-block exclusive scan: rowptr[0]=0, rowptr[i+1]=sum cnt[0..i]
__global__ void scan_kernel(const int* __restrict__ cnt, int* __restrict__ rowptr) {
    __shared__ int sdata[1024];
    __shared__ int s_running;
    const int tid = threadIdx.x;
    if (tid == 0) s_running = 0;
    __syncthreads();
    for (int base = 0; base < N_NODES; base += 1024) {
        int i = base + tid;
        int v = (i < N_NODES) ? cnt[i] : 0;
        sdata[tid] = v;
        __syncthreads();
#pragma unroll
        for (int off = 1; off < 1024; off <<= 1) {
            int t = (tid >= off) ? sdata[tid - off] : 0;
            __syncthreads();
            sdata[tid] += t;
            __syncthreads();
        }
        int run = s_running;
        if (i < N_NODES) rowptr[i + 1] = run + sdata[tid];
        __syncthreads();
        if (tid == 1023) s_running = run + sdata[1023];
        __syncthreads();
    }
    if (tid == 0) rowptr[0] = 0;
}

__global__ void fill_kernel(const int* __restrict__ ei, const int* __restrict__ rowptr,
                            int* __restrict__ cursor, int* __restrict__ csr_src) {
    int e = blockIdx.x * blockDim.x + threadIdx.x;
    if (e < N_EDGES) {
        int dst = ei[N_EDGES + e];
        int p = atomicAdd(&cursor[dst], 1);
        csr_src[rowptr[dst] + p] = ei[e];
    }
}

// one wave per node: agg[n] = h[n] + sum over csr srcs of h[src]
__global__ __launch_bounds__(256) void agg_kernel(const float* __restrict__ h,
                                                  const int* __restrict__ rowptr,
                                                  const int* __restrict__ csr_src,
                                                  float* __restrict__ agg) {
    int w = (blockIdx.x * 256 + threadIdx.x) >> 6;
    int lane = threadIdx.x & 63;
    if (w >= N_NODES) return;
    const float2* h2 = (const float2*)h;
    float2 acc = h2[(size_t)w * 64 + lane];   // self-loop
    int s = rowptr[w];
    int e = rowptr[w + 1];
    for (int i = s; i < e; ++i) {
        int src = csr_src[i];
        float2 v = h2[(size_t)src * 64 + lane];
        acc.x += v.x; acc.y += v.y;
    }
    ((float2*)agg)[(size_t)w * 64 + lane] = acc;
}

// h_out = relu(A @ W1 + b1) @ W2 + b2 ; 4 waves/block, 16 nodes/wave
__global__ __launch_bounds__(256) void mlp_kernel(const float* __restrict__ A,
                                                  const short* __restrict__ W1p,
                                                  const float* __restrict__ b1,
                                                  const short* __restrict__ W2p,
                                                  const float* __restrict__ b2,
                                                  float* __restrict__ Hout) {
    __shared__ short tbuf[4][16 * 144];
    const int tid = threadIdx.x;
    const int wid = tid >> 6;
    const int lane = tid & 63;
    const int l15 = lane & 15;
    const int lg = lane >> 4;              // 0..3
    const int node0 = blockIdx.x * 64 + wid * 16;

    // A fragments: lane holds A[node0+l15][kstep*32 + lg*8 + 0..7]
    int arow = node0 + l15;
    if (arow >= N_NODES) arow = N_NODES - 1;
    const float* ap = A + (size_t)arow * DIM + lg * 8;
    bf16x8 afr[4];
#pragma unroll
    for (int ks = 0; ks < 4; ++ks) {
        float4 lo = *(const float4*)(ap + ks * 32);
        float4 hi = *(const float4*)(ap + ks * 32 + 4);
        bf16x8 t;
        t[0] = f2bf(lo.x); t[1] = f2bf(lo.y); t[2] = f2bf(lo.z); t[3] = f2bf(lo.w);
        t[4] = f2bf(hi.x); t[5] = f2bf(hi.y); t[6] = f2bf(hi.z); t[7] = f2bf(hi.w);
        afr[ks] = t;
    }

    short* tb = tbuf[wid];
    // GEMM1 + bias + relu -> LDS (bf16)
#pragma unroll
    for (int nt = 0; nt < 8; ++nt) {
        f32x4 acc = {0.f, 0.f, 0.f, 0.f};
#pragma unroll
        for (int ks = 0; ks < 4; ++ks) {
            bf16x8 b = *(const bf16x8*)(W1p + (size_t)(((nt * 4 + ks) << 6) + lane) * 8);
            acc = __builtin_amdgcn_mfma_f32_16x16x32_bf16(afr[ks], b, acc, 0, 0, 0);
        }
        float bias = b1[nt * 16 + l15];
#pragma unroll
        for (int i = 0; i < 4; ++i) {
            int r = lg * 4 + i;
            float v = fmaxf(acc[i] + bias, 0.f);
            tb[r * 144 + nt * 16 + l15] = f2bf(v);
        }
    }
    __syncthreads();

    // A2 fragments from LDS: lane reads row l15, k = ks*32 + lg*8 .. +8 (contiguous 16B)
    bf16x8 a2[4];
#pragma unroll
    for (int ks = 0; ks < 4; ++ks)
        a2[ks] = *(const bf16x8*)(tb + l15 * 144 + ks * 32 + lg * 8);

    // GEMM2 + bias -> global f32
#pragma unroll
    for (int nt = 0; nt < 8; ++nt) {
        f32x4 acc = {0.f, 0.f, 0.f, 0.f};
#pragma unroll
        for (int ks = 0; ks < 4; ++ks) {
            bf16x8 b = *(const bf16x8*)(W2p + (size_t)(((nt * 4 + ks) << 6) + lane) * 8);
            acc = __builtin_amdgcn_mfma_f32_16x16x32_bf16(a2[ks], b, acc, 0, 0, 0);
        }
        float bias = b2[nt * 16 + l15];
#pragma unroll
        for (int i = 0; i < 4; ++i) {
            int node = node0 + lg * 4 + i;
            if (node < N_NODES) Hout[(size_t)node * DIM + nt * 16 + l15] = acc[i] + bias;
        }
    }
}

// one block (128 threads) per graph; x_batch is sorted
__global__ void pool_kernel(const float* __restrict__ h, const int* __restrict__ xb,
                            float* __restrict__ pooled) {
    int g = blockIdx.x;
    int f = threadIdx.x;
    int lo = 0, hi = N_NODES;
    while (lo < hi) { int m = (lo + hi) >> 1; if (xb[m] < g) lo = m + 1; else hi = m; }
    int s = lo;
    hi = N_NODES;
    while (lo < hi) { int m = (lo + hi) >> 1; if (xb[m] < g + 1) lo = m + 1; else hi = m; }
    int e = lo;
    float acc = 0.f;
    for (int i = s; i < e; ++i) acc += h[(size_t)i * DIM + f];
    float c = (e - s) > 0 ? (float)(e - s) : 1.0f;
    pooled[g * DIM + f] = acc / c;
}

// out[g] = relu(pooled[g] @ W1 + b1) @ W2 + b2 ; one block (128 threads) per graph
__global__ void reg_kernel(const float* __restrict__ pooled, const float* __restrict__ W1,
                           const float* __restrict__ b1, const float* __restrict__ W2,
                           const float* __restrict__ b2, float* __restrict__ out) {
    __shared__ float p[128];
    __shared__ float red[128];
    int g = blockIdx.x, t = threadIdx.x;
    p[t] = pooled[g * DIM + t];
    __syncthreads();
    float acc = b1[t];
#pragma unroll 8
    for (int k = 0; k < DIM; ++k) acc = fmaf(p[k], W1[k * DIM + t], acc);
    float r = fmaxf(acc, 0.f);
    red[t] = r * W2[t];
    __syncthreads();
    for (int off = 64; off; off >>= 1) {
        if (t < off) red[t] += red[t + off];
        __syncthreads();
    }
    if (t == 0) out[g] = red[0] + b2[0];
}

extern "C" void kernel_launch(void* const* d_in, const int* in_sizes, int n_in,
                              void* d_out, int out_size, void* d_ws, size_t ws_size,
                              hipStream_t stream) {
    (void)in_sizes; (void)n_in; (void)out_size; (void)ws_size;
    const float* x     = (const float*)d_in[0];
    const int*   ei    = (const int*)d_in[1];
    const int*   xb    = (const int*)d_in[3];
    const float* c0W1  = (const float*)d_in[4];
    const float* c0b1  = (const float*)d_in[5];
    const float* c0W2  = (const float*)d_in[6];
    const float* c0b2  = (const float*)d_in[7];
    const float* c1W1  = (const float*)d_in[8];
    const float* c1b1  = (const float*)d_in[9];
    const float* c1W2  = (const float*)d_in[10];
    const float* c1b2  = (const float*)d_in[11];
    const float* rW1   = (const float*)d_in[12];
    const float* rb1   = (const float*)d_in[13];
    const float* rW2   = (const float*)d_in[14];
    const float* rb2   = (const float*)d_in[15];
    float* out = (float*)d_out;

    char* ws = (char*)d_ws;
    size_t off = 0;
    auto alloc = [&](size_t bytes) -> char* {
        char* p = ws + off;
        off = (off + bytes + 511) & ~(size_t)511;
        return p;
    };
    int*   zeros  = (int*)alloc((size_t)2 * N_NODES * 4);      // cnt | cursor
    int*   cnt    = zeros;
    int*   cursor = zeros + N_NODES;
    int*   rowptr = (int*)alloc((size_t)(N_NODES + 1) * 4);
    int*   csr    = (int*)alloc((size_t)N_EDGES * 4);
    float* agg    = (float*)alloc((size_t)N_NODES * DIM * 4);
    float* hbuf   = (float*)alloc((size_t)N_NODES * DIM * 4);
    float* pooled = (float*)alloc((size_t)N_GRAPHS * DIM * 4);
    short* Wp     = (short*)alloc((size_t)4 * DIM * DIM * 2);

    hipMemsetAsync(zeros, 0, (size_t)2 * N_NODES * 4, stream);

    // pack conv weights to bf16 fragment order
    pack_w_kernel<<<8, 256, 0, stream>>>(c0W1, Wp + 0 * 16384);
    pack_w_kernel<<<8, 256, 0, stream>>>(c0W2, Wp + 1 * 16384);
    pack_w_kernel<<<8, 256, 0, stream>>>(c1W1, Wp + 2 * 16384);
    pack_w_kernel<<<8, 256, 0, stream>>>(c1W2, Wp + 3 * 16384);

    // CSR by destination
    const int EB = (N_EDGES + 255) / 256;
    count_kernel<<<EB, 256, 0, stream>>>(ei, cnt);
    scan_kernel<<<1, 1024, 0, stream>>>(cnt, rowptr);
    fill_kernel<<<EB, 256, 0, stream>>>(ei, rowptr, cursor, csr);

    const int AB = (N_NODES + 3) / 4;     // 4 nodes (waves) per block
    const int MB = (N_NODES + 63) / 64;   // 64 nodes per block

    // layer 0
    agg_kernel<<<AB, 256, 0, stream>>>(x, rowptr, csr, agg);
    mlp_kernel<<<MB, 256, 0, stream>>>(agg, Wp + 0 * 16384, c0b1, Wp + 1 * 16384, c0b2, hbuf);
    // layer 1
    agg_kernel<<<AB, 256, 0, stream>>>(hbuf, rowptr, csr, agg);
    mlp_kernel<<<MB, 256, 0, stream>>>(agg, Wp + 2 * 16384, c1b1, Wp + 3 * 16384, c1b2, hbuf);

    // pool + regressor
    pool_kernel<<<N_GRAPHS, 128, 0, stream>>>(hbuf, xb, pooled);
    reg_kernel<<<N_GRAPHS, 128, 0, stream>>>(pooled, rW1, rb1, rW2, rb2, out);
}

// Round 2
// 285.255 us; speedup vs baseline: 1.3161x; 1.3161x over previous
//
#include <hip/hip_runtime.h>
#include <stdint.h>

#define N_NODES 50000
#define N_EDGES 600000
#define DIM     128
#define N_GRAPHS 512
#define NB_SCAN 49            // ceil(50000/1024)

typedef __attribute__((ext_vector_type(8))) short bf16x8;
typedef __attribute__((ext_vector_type(4))) float f32x4;

__device__ __forceinline__ short f2bf(float f) {
    union { float f; uint32_t u; } c; c.f = f;
    uint32_t u = c.u;
    u += 0x7fffu + ((u >> 16) & 1u);   // round-to-nearest-even
    return (short)(u >> 16);
}
__device__ __forceinline__ float bflo(uint32_t u) {   // low 16 bits as bf16 -> f32
    union { uint32_t u; float f; } c; c.u = u << 16; return c.f;
}
__device__ __forceinline__ float bfhi(uint32_t u) {   // high 16 bits as bf16 -> f32
    union { uint32_t u; float f; } c; c.u = u & 0xffff0000u; return c.f;
}

// ---- convert f32 rows -> bf16 (8 elems/thread) ----
__global__ void cvt_kernel(const float* __restrict__ in, ushort* __restrict__ out, int n8) {
    int i = blockIdx.x * blockDim.x + threadIdx.x;
    if (i >= n8) return;
    const float4* p = (const float4*)(in + (size_t)i * 8);
    float4 lo = p[0], hi = p[1];
    bf16x8 t;
    t[0] = f2bf(lo.x); t[1] = f2bf(lo.y); t[2] = f2bf(lo.z); t[3] = f2bf(lo.w);
    t[4] = f2bf(hi.x); t[5] = f2bf(hi.y); t[6] = f2bf(hi.z); t[7] = f2bf(hi.w);
    *(bf16x8*)(out + (size_t)i * 8) = t;
}

// ---- pack four 128x128 f32 row-major W into bf16 B-fragment order ----
// per matrix: frag idx = (ntile*4 + kstep)*64 + lane ; element j = W[k0+j][col]
// col = ntile*16 + (lane&15), k0 = kstep*32 + (lane>>4)*8
__global__ void pack_w4_kernel(const float* __restrict__ W0, const float* __restrict__ W1,
                               const float* __restrict__ W2, const float* __restrict__ W3,
                               short* __restrict__ Wp) {
    int idx = blockIdx.x * blockDim.x + threadIdx.x;   // 0..8191
    if (idx >= 8192) return;
    int m = idx >> 11;
    int r = idx & 2047;
    const float* W = (m == 0) ? W0 : (m == 1) ? W1 : (m == 2) ? W2 : W3;
    int lane = r & 63;
    int ks = (r >> 6) & 3;
    int nt = r >> 8;
    int col = nt * 16 + (lane & 15);
    int k0 = ks * 32 + ((lane >> 4) << 3);
    short* dst = Wp + (size_t)idx * 8;
#pragma unroll
    for (int j = 0; j < 8; ++j) dst[j] = f2bf(W[(k0 + j) * DIM + col]);
}

__global__ void count_kernel(const int* __restrict__ ei, int* __restrict__ cnt) {
    int e = blockIdx.x * blockDim.x + threadIdx.x;
    if (e < N_EDGES) atomicAdd(&cnt[ei[N_EDGES + e]], 1);
}

// ---- hierarchical scan: 49-block partial sums -> tiny scan -> local scan + base ----
__global__ void blocksum_kernel(const int* __restrict__ cnt, int* __restrict__ partial) {
    __shared__ int s[1024];
    int i = blockIdx.x * 1024 + threadIdx.x;
    s[threadIdx.x] = (i < N_NODES) ? cnt[i] : 0;
    __syncthreads();
#pragma unroll
    for (int off = 512; off; off >>= 1) {
        if (threadIdx.x < off) s[threadIdx.x] += s[threadIdx.x + off];
        __syncthreads();
    }
    if (threadIdx.x == 0) partial[blockIdx.x] = s[0];
}

__global__ void scanpartial_kernel(const int* __restrict__ partial, int* __restrict__ pbase) {
    __shared__ int s[64];
    int t = threadIdx.x;
    s[t] = (t < NB_SCAN) ? partial[t] : 0;
    __syncthreads();
#pragma unroll
    for (int off = 1; off < 64; off <<= 1) {
        int v = (t >= off) ? s[t - off] : 0;
        __syncthreads();
        s[t] += v;
        __syncthreads();
    }
    if (t < NB_SCAN) pbase[t] = (t == 0) ? 0 : s[t - 1];
}

__global__ void rowptr_kernel(const int* __restrict__ cnt, const int* __restrict__ pbase,
                              int* __restrict__ rowptr) {
    __shared__ int s[1024];
    int b = blockIdx.x, t = threadIdx.x;
    int i = b * 1024 + t;
    s[t] = (i < N_NODES) ? cnt[i] : 0;
    __syncthreads();
#pragma unroll
    for (int off = 1; off < 1024; off <<= 1) {
        int v = (t >= off) ? s[t - off] : 0;
        __syncthreads();
        s[t] += v;
        __syncthreads();
    }
    if (i < N_NODES) rowptr[i + 1] = pbase[b] + s[t];
    if (i == 0) rowptr[0] = 0;
}

__global__ void fill_kernel(const int* __restrict__ ei, const int* __restrict__ rowptr,
                            int* __restrict__ cursor, int* __restrict__ csr_src) {
    int e = blockIdx.x * blockDim.x + threadIdx.x;
    if (e < N_EDGES) {
        int dst = ei[N_EDGES + e];
        int p = atomicAdd(&cursor[dst], 1);
        csr_src[rowptr[dst] + p] = ei[e];
    }
}

// one wave per node, bf16 rows (256B = 64 lanes x 4B): agg[n] = h[n] + sum h[src]
__global__ __launch_bounds__(256) void agg_kernel(const ushort* __restrict__ h,
                                                  const int* __restrict__ rowptr,
                                                  const int* __restrict__ csr_src,
                                                  ushort* __restrict__ agg) {
    int w = (blockIdx.x * 256 + threadIdx.x) >> 6;
    int lane = threadIdx.x & 63;
    if (w >= N_NODES) return;
    const uint32_t* h1 = (const uint32_t*)h;
    uint32_t u = h1[(size_t)w * 64 + lane];   // self-loop
    float ax = bflo(u), ay = bfhi(u);
    int s = rowptr[w];
    int e = rowptr[w + 1];
    for (int i = s; i < e; ++i) {
        uint32_t v = h1[(size_t)csr_src[i] * 64 + lane];
        ax += bflo(v); ay += bfhi(v);
    }
    uint32_t r = (uint32_t)(uint16_t)f2bf(ax) | ((uint32_t)(uint16_t)f2bf(ay) << 16);
    ((uint32_t*)agg)[(size_t)w * 64 + lane] = r;
}

// h_out = relu(A @ W1 + b1) @ W2 + b2 ; bf16 in, bf16 out; 4 waves/block, 16 nodes/wave
__global__ __launch_bounds__(256) void mlp_kernel(const ushort* __restrict__ A,
                                                  const short* __restrict__ W1p,
                                                  const float* __restrict__ b1,
                                                  const short* __restrict__ W2p,
                                                  const float* __restrict__ b2,
                                                  ushort* __restrict__ Hout) {
    __shared__ short tbuf[4][16 * 144];
    const int tid = threadIdx.x;
    const int wid = tid >> 6;
    const int lane = tid & 63;
    const int l15 = lane & 15;
    const int lg = lane >> 4;              // 0..3
    const int node0 = blockIdx.x * 64 + wid * 16;

    // A fragments: lane holds A[node0+l15][ks*32 + lg*8 + 0..7] (16B bf16 loads)
    int arow = node0 + l15;
    if (arow >= N_NODES) arow = N_NODES - 1;
    const short* ap = (const short*)A + (size_t)arow * DIM + lg * 8;
    bf16x8 afr[4];
#pragma unroll
    for (int ks = 0; ks < 4; ++ks) afr[ks] = *(const bf16x8*)(ap + ks * 32);

    short* tb = tbuf[wid];
    // GEMM1 + bias + relu -> LDS (bf16)
#pragma unroll
    for (int nt = 0; nt < 8; ++nt) {
        f32x4 acc = {0.f, 0.f, 0.f, 0.f};
#pragma unroll
        for (int ks = 0; ks < 4; ++ks) {
            bf16x8 b = *(const bf16x8*)(W1p + (size_t)(((nt * 4 + ks) << 6) + lane) * 8);
            acc = __builtin_amdgcn_mfma_f32_16x16x32_bf16(afr[ks], b, acc, 0, 0, 0);
        }
        float bias = b1[nt * 16 + l15];
#pragma unroll
        for (int i = 0; i < 4; ++i) {
            int r = lg * 4 + i;
            float v = fmaxf(acc[i] + bias, 0.f);
            tb[r * 144 + nt * 16 + l15] = f2bf(v);
        }
    }
    __syncthreads();

    // A2 fragments from LDS: row l15, k = ks*32 + lg*8 (contiguous 16B)
    bf16x8 a2[4];
#pragma unroll
    for (int ks = 0; ks < 4; ++ks)
        a2[ks] = *(const bf16x8*)(tb + l15 * 144 + ks * 32 + lg * 8);
    __syncthreads();

    // GEMM2 + bias -> LDS (bf16), then coalesced global writes
#pragma unroll
    for (int nt = 0; nt < 8; ++nt) {
        f32x4 acc = {0.f, 0.f, 0.f, 0.f};
#pragma unroll
        for (int ks = 0; ks < 4; ++ks) {
            bf16x8 b = *(const bf16x8*)(W2p + (size_t)(((nt * 4 + ks) << 6) + lane) * 8);
            acc = __builtin_amdgcn_mfma_f32_16x16x32_bf16(a2[ks], b, acc, 0, 0, 0);
        }
        float bias = b2[nt * 16 + l15];
#pragma unroll
        for (int i = 0; i < 4; ++i) {
            int r = lg * 4 + i;
            tb[r * 144 + nt * 16 + l15] = f2bf(acc[i] + bias);
        }
    }
    __syncthreads();

    // write 16 rows x 128 bf16: 4 iterations x 64 lanes x 16B
#pragma unroll
    for (int it = 0; it < 4; ++it) {
        int chunk = it * 64 + lane;    // 0..255
        int row = chunk >> 4;          // 0..15
        int seg = chunk & 15;          // 16B segment within row
        bf16x8 v = *(const bf16x8*)(tb + row * 144 + seg * 8);
        int node = node0 + row;
        if (node < N_NODES) *(bf16x8*)((short*)Hout + (size_t)node * DIM + seg * 8) = v;
    }
}

// one block (128 threads) per graph; x_batch sorted; bf16 h
__global__ void pool_kernel(const ushort* __restrict__ h, const int* __restrict__ xb,
                            float* __restrict__ pooled) {
    int g = blockIdx.x;
    int f = threadIdx.x;
    int lo = 0, hi = N_NODES;
    while (lo < hi) { int m = (lo + hi) >> 1; if (xb[m] < g) lo = m + 1; else hi = m; }
    int s = lo;
    hi = N_NODES;
    while (lo < hi) { int m = (lo + hi) >> 1; if (xb[m] < g + 1) lo = m + 1; else hi = m; }
    int e = lo;
    float acc = 0.f;
    for (int i = s; i < e; ++i) {
        union { uint32_t u; float f; } c;
        c.u = ((uint32_t)h[(size_t)i * DIM + f]) << 16;
        acc += c.f;
    }
    float c = (e - s) > 0 ? (float)(e - s) : 1.0f;
    pooled[g * DIM + f] = acc / c;
}

// out[g] = relu(pooled[g] @ W1 + b1) @ W2 + b2 ; one block (128 threads) per graph
__global__ void reg_kernel(const float* __restrict__ pooled, const float* __restrict__ W1,
                           const float* __restrict__ b1, const float* __restrict__ W2,
                           const float* __restrict__ b2, float* __restrict__ out) {
    __shared__ float p[128];
    __shared__ float red[128];
    int g = blockIdx.x, t = threadIdx.x;
    p[t] = pooled[g * DIM + t];
    __syncthreads();
    float acc = b1[t];
#pragma unroll 8
    for (int k = 0; k < DIM; ++k) acc = fmaf(p[k], W1[k * DIM + t], acc);
    float r = fmaxf(acc, 0.f);
    red[t] = r * W2[t];
    __syncthreads();
    for (int off = 64; off; off >>= 1) {
        if (t < off) red[t] += red[t + off];
        __syncthreads();
    }
    if (t == 0) out[g] = red[0] + b2[0];
}

extern "C" void kernel_launch(void* const* d_in, const int* in_sizes, int n_in,
                              void* d_out, int out_size, void* d_ws, size_t ws_size,
                              hipStream_t stream) {
    (void)in_sizes; (void)n_in; (void)out_size; (void)ws_size;
    const float* x     = (const float*)d_in[0];
    const int*   ei    = (const int*)d_in[1];
    const int*   xb    = (const int*)d_in[3];
    const float* c0W1  = (const float*)d_in[4];
    const float* c0b1  = (const float*)d_in[5];
    const float* c0W2  = (const float*)d_in[6];
    const float* c0b2  = (const float*)d_in[7];
    const float* c1W1  = (const float*)d_in[8];
    const float* c1b1  = (const float*)d_in[9];
    const float* c1W2  = (const float*)d_in[10];
    const float* c1b2  = (const float*)d_in[11];
    const float* rW1   = (const float*)d_in[12];
    const float* rb1   = (const float*)d_in[13];
    const float* rW2   = (const float*)d_in[14];
    const float* rb2   = (const float*)d_in[15];
    float* out = (float*)d_out;

    char* ws = (char*)d_ws;
    size_t off = 0;
    auto alloc = [&](size_t bytes) -> char* {
        char* p = ws + off;
        off = (off + bytes + 511) & ~(size_t)511;
        return p;
    };
    int*    zeros  = (int*)alloc((size_t)2 * N_NODES * 4);      // cnt | cursor
    int*    cnt    = zeros;
    int*    cursor = zeros + N_NODES;
    int*    rowptr = (int*)alloc((size_t)(N_NODES + 1) * 4);
    int*    csr    = (int*)alloc((size_t)N_EDGES * 4);
    int*    partial= (int*)alloc((size_t)64 * 4);
    int*    pbase  = (int*)alloc((size_t)64 * 4);
    ushort* xbf    = (ushort*)alloc((size_t)N_NODES * DIM * 2);
    ushort* aggbf  = (ushort*)alloc((size_t)N_NODES * DIM * 2);
    ushort* hbf    = (ushort*)alloc((size_t)N_NODES * DIM * 2);
    float*  pooled = (float*)alloc((size_t)N_GRAPHS * DIM * 4);
    short*  Wp     = (short*)alloc((size_t)4 * DIM * DIM * 2);

    hipMemsetAsync(zeros, 0, (size_t)2 * N_NODES * 4, stream);

    // weight pack (all 4 conv matrices) + x -> bf16
    pack_w4_kernel<<<32, 256, 0, stream>>>(c0W1, c0W2, c1W1, c1W2, Wp);
    const int n8 = N_NODES * DIM / 8;
    cvt_kernel<<<(n8 + 255) / 256, 256, 0, stream>>>(x, xbf, n8);

    // CSR by destination (hierarchical scan)
    const int EB = (N_EDGES + 255) / 256;
    count_kernel<<<EB, 256, 0, stream>>>(ei, cnt);
    blocksum_kernel<<<NB_SCAN, 1024, 0, stream>>>(cnt, partial);
    scanpartial_kernel<<<1, 64, 0, stream>>>(partial, pbase);
    rowptr_kernel<<<NB_SCAN, 1024, 0, stream>>>(cnt, pbase, rowptr);
    fill_kernel<<<EB, 256, 0, stream>>>(ei, rowptr, cursor, csr);

    const int AB = (N_NODES + 3) / 4;     // 4 nodes (waves) per block
    const int MB = (N_NODES + 63) / 64;   // 64 nodes per block

    // layer 0
    agg_kernel<<<AB, 256, 0, stream>>>(xbf, rowptr, csr, aggbf);
    mlp_kernel<<<MB, 256, 0, stream>>>(aggbf, Wp + 0 * 16384, c0b1, Wp + 1 * 16384, c0b2, hbf);
    // layer 1
    agg_kernel<<<AB, 256, 0, stream>>>(hbf, rowptr, csr, aggbf);
    mlp_kernel<<<MB, 256, 0, stream>>>(aggbf, Wp + 2 * 16384, c1b1, Wp + 3 * 16384, c1b2, hbf);

    // pool + regressor
    pool_kernel<<<N_GRAPHS, 128, 0, stream>>>(hbf, xb, pooled);
    reg_kernel<<<N_GRAPHS, 128, 0, stream>>>(pooled, rW1, rb1, rW2, rb2, out);
}

// Round 3
// 214.815 us; speedup vs baseline: 1.7477x; 1.3279x over previous
//
#include <hip/hip_runtime.h>
#include <stdint.h>

#define N_NODES 50000
#define N_EDGES 600000
#define DIM     128
#define N_GRAPHS 512
#define NB_SCAN 49            // ceil(50000/1024)

typedef __attribute__((ext_vector_type(8))) short bf16x8;
typedef __attribute__((ext_vector_type(4))) float f32x4;

__device__ __forceinline__ short f2bf(float f) {
    union { float f; uint32_t u; } c; c.f = f;
    uint32_t u = c.u;
    u += 0x7fffu + ((u >> 16) & 1u);   // round-to-nearest-even
    return (short)(u >> 16);
}
__device__ __forceinline__ float bflo(uint32_t u) {
    union { uint32_t u; float f; } c; c.u = u << 16; return c.f;
}
__device__ __forceinline__ float bfhi(uint32_t u) {
    union { uint32_t u; float f; } c; c.u = u & 0xffff0000u; return c.f;
}

// ---- convert f32 rows -> bf16 (8 elems/thread) ----
__global__ void cvt_kernel(const float* __restrict__ in, ushort* __restrict__ out, int n8) {
    int i = blockIdx.x * blockDim.x + threadIdx.x;
    if (i >= n8) return;
    const float4* p = (const float4*)(in + (size_t)i * 8);
    float4 lo = p[0], hi = p[1];
    bf16x8 t;
    t[0] = f2bf(lo.x); t[1] = f2bf(lo.y); t[2] = f2bf(lo.z); t[3] = f2bf(lo.w);
    t[4] = f2bf(hi.x); t[5] = f2bf(hi.y); t[6] = f2bf(hi.z); t[7] = f2bf(hi.w);
    *(bf16x8*)(out + (size_t)i * 8) = t;
}

// ---- pack four 128x128 f32 row-major W into bf16 B-fragment order ----
__global__ void pack_w4_kernel(const float* __restrict__ W0, const float* __restrict__ W1,
                               const float* __restrict__ W2, const float* __restrict__ W3,
                               short* __restrict__ Wp) {
    int idx = blockIdx.x * blockDim.x + threadIdx.x;   // 0..8191
    if (idx >= 8192) return;
    int m = idx >> 11;
    int r = idx & 2047;
    const float* W = (m == 0) ? W0 : (m == 1) ? W1 : (m == 2) ? W2 : W3;
    int lane = r & 63;
    int ks = (r >> 6) & 3;
    int nt = r >> 8;
    int col = nt * 16 + (lane & 15);
    int k0 = ks * 32 + ((lane >> 4) << 3);
    short* dst = Wp + (size_t)idx * 8;
#pragma unroll
    for (int j = 0; j < 8; ++j) dst[j] = f2bf(W[(k0 + j) * DIM + col]);
}

__global__ void count_kernel(const int* __restrict__ ei, int* __restrict__ cnt) {
    int e = blockIdx.x * blockDim.x + threadIdx.x;
    if (e < N_EDGES) atomicAdd(&cnt[ei[N_EDGES + e]], 1);
}

// ---- hierarchical scan ----
__global__ void blocksum_kernel(const int* __restrict__ cnt, int* __restrict__ partial) {
    __shared__ int s[1024];
    int i = blockIdx.x * 1024 + threadIdx.x;
    s[threadIdx.x] = (i < N_NODES) ? cnt[i] : 0;
    __syncthreads();
#pragma unroll
    for (int off = 512; off; off >>= 1) {
        if (threadIdx.x < off) s[threadIdx.x] += s[threadIdx.x + off];
        __syncthreads();
    }
    if (threadIdx.x == 0) partial[blockIdx.x] = s[0];
}

__global__ void scanpartial_kernel(const int* __restrict__ partial, int* __restrict__ pbase) {
    __shared__ int s[64];
    int t = threadIdx.x;
    s[t] = (t < NB_SCAN) ? partial[t] : 0;
    __syncthreads();
#pragma unroll
    for (int off = 1; off < 64; off <<= 1) {
        int v = (t >= off) ? s[t - off] : 0;
        __syncthreads();
        s[t] += v;
        __syncthreads();
    }
    if (t < NB_SCAN) pbase[t] = (t == 0) ? 0 : s[t - 1];
}

__global__ void rowptr_kernel(const int* __restrict__ cnt, const int* __restrict__ pbase,
                              int* __restrict__ rowptr) {
    __shared__ int s[1024];
    int b = blockIdx.x, t = threadIdx.x;
    int i = b * 1024 + t;
    s[t] = (i < N_NODES) ? cnt[i] : 0;
    __syncthreads();
#pragma unroll
    for (int off = 1; off < 1024; off <<= 1) {
        int v = (t >= off) ? s[t - off] : 0;
        __syncthreads();
        s[t] += v;
        __syncthreads();
    }
    if (i < N_NODES) rowptr[i + 1] = pbase[b] + s[t];
    if (i == 0) rowptr[0] = 0;
}

__global__ void fill_kernel(const int* __restrict__ ei, const int* __restrict__ rowptr,
                            int* __restrict__ cursor, int* __restrict__ csr_src) {
    int e = blockIdx.x * blockDim.x + threadIdx.x;
    if (e < N_EDGES) {
        int dst = ei[N_EDGES + e];
        int p = atomicAdd(&cursor[dst], 1);
        csr_src[rowptr[dst] + p] = ei[e];
    }
}

// one wave per node; 4 lane-groups of 16 process 4 edges concurrently, 16B/lane
// group lg handles edges s+lg, s+lg+4, ... ; 2x unrolled -> 8 edges in flight
__global__ __launch_bounds__(256) void agg_kernel(const ushort* __restrict__ h,
                                                  const int* __restrict__ rowptr,
                                                  const int* __restrict__ csr_src,
                                                  ushort* __restrict__ agg) {
    int w = (blockIdx.x * 256 + threadIdx.x) >> 6;
    int lane = threadIdx.x & 63;
    if (w >= N_NODES) return;
    const int l15 = lane & 15;
    const int lg = lane >> 4;
    const uint4* h4 = (const uint4*)h;      // 16 segments of 16B per row

    float a0=0,a1=0,a2=0,a3=0,a4=0,a5=0,a6=0,a7=0;
    if (lg == 0) {                          // self-loop in group 0
        uint4 v = h4[(size_t)w * 16 + l15];
        a0 = bflo(v.x); a1 = bfhi(v.x); a2 = bflo(v.y); a3 = bfhi(v.y);
        a4 = bflo(v.z); a5 = bfhi(v.z); a6 = bflo(v.w); a7 = bfhi(v.w);
    }

    const int s = rowptr[w];
    const int e = rowptr[w + 1];
    int i = s + lg;
    // 2 slots per iteration (8 edges in flight across the wave)
    for (; i + 4 < e; i += 8) {
        int idx0 = csr_src[i];
        int idx1 = csr_src[i + 4];
        uint4 v0 = h4[(size_t)idx0 * 16 + l15];
        uint4 v1 = h4[(size_t)idx1 * 16 + l15];
        a0 += bflo(v0.x); a1 += bfhi(v0.x); a2 += bflo(v0.y); a3 += bfhi(v0.y);
        a4 += bflo(v0.z); a5 += bfhi(v0.z); a6 += bflo(v0.w); a7 += bfhi(v0.w);
        a0 += bflo(v1.x); a1 += bfhi(v1.x); a2 += bflo(v1.y); a3 += bfhi(v1.y);
        a4 += bflo(v1.z); a5 += bfhi(v1.z); a6 += bflo(v1.w); a7 += bfhi(v1.w);
    }
    if (i < e) {
        int idx0 = csr_src[i];
        uint4 v0 = h4[(size_t)idx0 * 16 + l15];
        a0 += bflo(v0.x); a1 += bfhi(v0.x); a2 += bflo(v0.y); a3 += bfhi(v0.y);
        a4 += bflo(v0.z); a5 += bfhi(v0.z); a6 += bflo(v0.w); a7 += bfhi(v0.w);
    }

    // combine the 4 groups (same l15, different lg)
#pragma unroll
    for (int m = 16; m <= 32; m <<= 1) {
        a0 += __shfl_xor(a0, m); a1 += __shfl_xor(a1, m);
        a2 += __shfl_xor(a2, m); a3 += __shfl_xor(a3, m);
        a4 += __shfl_xor(a4, m); a5 += __shfl_xor(a5, m);
        a6 += __shfl_xor(a6, m); a7 += __shfl_xor(a7, m);
    }

    if (lg == 0) {
        uint4 r;
        r.x = (uint32_t)(uint16_t)f2bf(a0) | ((uint32_t)(uint16_t)f2bf(a1) << 16);
        r.y = (uint32_t)(uint16_t)f2bf(a2) | ((uint32_t)(uint16_t)f2bf(a3) << 16);
        r.z = (uint32_t)(uint16_t)f2bf(a4) | ((uint32_t)(uint16_t)f2bf(a5) << 16);
        r.w = (uint32_t)(uint16_t)f2bf(a6) | ((uint32_t)(uint16_t)f2bf(a7) << 16);
        ((uint4*)agg)[(size_t)w * 16 + l15] = r;
    }
}

// h_out = relu(A @ W1 + b1) @ W2 + b2 ; bf16 in, bf16 out; 4 waves/block, 16 nodes/wave
__global__ __launch_bounds__(256) void mlp_kernel(const ushort* __restrict__ A,
                                                  const short* __restrict__ W1p,
                                                  const float* __restrict__ b1,
                                                  const short* __restrict__ W2p,
                                                  const float* __restrict__ b2,
                                                  ushort* __restrict__ Hout) {
    __shared__ short tbuf[4][16 * 144];
    const int tid = threadIdx.x;
    const int wid = tid >> 6;
    const int lane = tid & 63;
    const int l15 = lane & 15;
    const int lg = lane >> 4;              // 0..3
    const int node0 = blockIdx.x * 64 + wid * 16;

    int arow = node0 + l15;
    if (arow >= N_NODES) arow = N_NODES - 1;
    const short* ap = (const short*)A + (size_t)arow * DIM + lg * 8;
    bf16x8 afr[4];
#pragma unroll
    for (int ks = 0; ks < 4; ++ks) afr[ks] = *(const bf16x8*)(ap + ks * 32);

    short* tb = tbuf[wid];
#pragma unroll
    for (int nt = 0; nt < 8; ++nt) {
        f32x4 acc = {0.f, 0.f, 0.f, 0.f};
#pragma unroll
        for (int ks = 0; ks < 4; ++ks) {
            bf16x8 b = *(const bf16x8*)(W1p + (size_t)(((nt * 4 + ks) << 6) + lane) * 8);
            acc = __builtin_amdgcn_mfma_f32_16x16x32_bf16(afr[ks], b, acc, 0, 0, 0);
        }
        float bias = b1[nt * 16 + l15];
#pragma unroll
        for (int i = 0; i < 4; ++i) {
            int r = lg * 4 + i;
            float v = fmaxf(acc[i] + bias, 0.f);
            tb[r * 144 + nt * 16 + l15] = f2bf(v);
        }
    }
    __syncthreads();

    bf16x8 a2[4];
#pragma unroll
    for (int ks = 0; ks < 4; ++ks)
        a2[ks] = *(const bf16x8*)(tb + l15 * 144 + ks * 32 + lg * 8);
    __syncthreads();

#pragma unroll
    for (int nt = 0; nt < 8; ++nt) {
        f32x4 acc = {0.f, 0.f, 0.f, 0.f};
#pragma unroll
        for (int ks = 0; ks < 4; ++ks) {
            bf16x8 b = *(const bf16x8*)(W2p + (size_t)(((nt * 4 + ks) << 6) + lane) * 8);
            acc = __builtin_amdgcn_mfma_f32_16x16x32_bf16(a2[ks], b, acc, 0, 0, 0);
        }
        float bias = b2[nt * 16 + l15];
#pragma unroll
        for (int i = 0; i < 4; ++i) {
            int r = lg * 4 + i;
            tb[r * 144 + nt * 16 + l15] = f2bf(acc[i] + bias);
        }
    }
    __syncthreads();

#pragma unroll
    for (int it = 0; it < 4; ++it) {
        int chunk = it * 64 + lane;
        int row = chunk >> 4;
        int seg = chunk & 15;
        bf16x8 v = *(const bf16x8*)(tb + row * 144 + seg * 8);
        int node = node0 + row;
        if (node < N_NODES) *(bf16x8*)((short*)Hout + (size_t)node * DIM + seg * 8) = v;
    }
}

// one block (128 threads) per graph; x_batch sorted; bf16 h
__global__ void pool_kernel(const ushort* __restrict__ h, const int* __restrict__ xb,
                            float* __restrict__ pooled) {
    int g = blockIdx.x;
    int f = threadIdx.x;
    int lo = 0, hi = N_NODES;
    while (lo < hi) { int m = (lo + hi) >> 1; if (xb[m] < g) lo = m + 1; else hi = m; }
    int s = lo;
    hi = N_NODES;
    while (lo < hi) { int m = (lo + hi) >> 1; if (xb[m] < g + 1) lo = m + 1; else hi = m; }
    int e = lo;
    float acc = 0.f;
    for (int i = s; i < e; ++i) {
        union { uint32_t u; float f; } c;
        c.u = ((uint32_t)h[(size_t)i * DIM + f]) << 16;
        acc += c.f;
    }
    float c = (e - s) > 0 ? (float)(e - s) : 1.0f;
    pooled[g * DIM + f] = acc / c;
}

__global__ void reg_kernel(const float* __restrict__ pooled, const float* __restrict__ W1,
                           const float* __restrict__ b1, const float* __restrict__ W2,
                           const float* __restrict__ b2, float* __restrict__ out) {
    __shared__ float p[128];
    __shared__ float red[128];
    int g = blockIdx.x, t = threadIdx.x;
    p[t] = pooled[g * DIM + t];
    __syncthreads();
    float acc = b1[t];
#pragma unroll 8
    for (int k = 0; k < DIM; ++k) acc = fmaf(p[k], W1[k * DIM + t], acc);
    float r = fmaxf(acc, 0.f);
    red[t] = r * W2[t];
    __syncthreads();
    for (int off = 64; off; off >>= 1) {
        if (t < off) red[t] += red[t + off];
        __syncthreads();
    }
    if (t == 0) out[g] = red[0] + b2[0];
}

extern "C" void kernel_launch(void* const* d_in, const int* in_sizes, int n_in,
                              void* d_out, int out_size, void* d_ws, size_t ws_size,
                              hipStream_t stream) {
    (void)in_sizes; (void)n_in; (void)out_size; (void)ws_size;
    const float* x     = (const float*)d_in[0];
    const int*   ei    = (const int*)d_in[1];
    const int*   xb    = (const int*)d_in[3];
    const float* c0W1  = (const float*)d_in[4];
    const float* c0b1  = (const float*)d_in[5];
    const float* c0W2  = (const float*)d_in[6];
    const float* c0b2  = (const float*)d_in[7];
    const float* c1W1  = (const float*)d_in[8];
    const float* c1b1  = (const float*)d_in[9];
    const float* c1W2  = (const float*)d_in[10];
    const float* c1b2  = (const float*)d_in[11];
    const float* rW1   = (const float*)d_in[12];
    const float* rb1   = (const float*)d_in[13];
    const float* rW2   = (const float*)d_in[14];
    const float* rb2   = (const float*)d_in[15];
    float* out = (float*)d_out;

    char* ws = (char*)d_ws;
    size_t off = 0;
    auto alloc = [&](size_t bytes) -> char* {
        char* p = ws + off;
        off = (off + bytes + 511) & ~(size_t)511;
        return p;
    };
    int*    zeros  = (int*)alloc((size_t)2 * N_NODES * 4);      // cnt | cursor
    int*    cnt    = zeros;
    int*    cursor = zeros + N_NODES;
    int*    rowptr = (int*)alloc((size_t)(N_NODES + 1) * 4);
    int*    csr    = (int*)alloc((size_t)N_EDGES * 4);
    int*    partial= (int*)alloc((size_t)64 * 4);
    int*    pbase  = (int*)alloc((size_t)64 * 4);
    ushort* xbf    = (ushort*)alloc((size_t)N_NODES * DIM * 2);
    ushort* aggbf  = (ushort*)alloc((size_t)N_NODES * DIM * 2);
    ushort* hbf    = (ushort*)alloc((size_t)N_NODES * DIM * 2);
    float*  pooled = (float*)alloc((size_t)N_GRAPHS * DIM * 4);
    short*  Wp     = (short*)alloc((size_t)4 * DIM * DIM * 2);

    hipMemsetAsync(zeros, 0, (size_t)2 * N_NODES * 4, stream);

    pack_w4_kernel<<<32, 256, 0, stream>>>(c0W1, c0W2, c1W1, c1W2, Wp);
    const int n8 = N_NODES * DIM / 8;
    cvt_kernel<<<(n8 + 255) / 256, 256, 0, stream>>>(x, xbf, n8);

    const int EB = (N_EDGES + 255) / 256;
    count_kernel<<<EB, 256, 0, stream>>>(ei, cnt);
    blocksum_kernel<<<NB_SCAN, 1024, 0, stream>>>(cnt, partial);
    scanpartial_kernel<<<1, 64, 0, stream>>>(partial, pbase);
    rowptr_kernel<<<NB_SCAN, 1024, 0, stream>>>(cnt, pbase, rowptr);
    fill_kernel<<<EB, 256, 0, stream>>>(ei, rowptr, cursor, csr);

    const int AB = (N_NODES + 3) / 4;     // 4 nodes (waves) per block
    const int MB = (N_NODES + 63) / 64;   // 64 nodes per block

    agg_kernel<<<AB, 256, 0, stream>>>(xbf, rowptr, csr, aggbf);
    mlp_kernel<<<MB, 256, 0, stream>>>(aggbf, Wp + 0 * 16384, c0b1, Wp + 1 * 16384, c0b2, hbf);
    agg_kernel<<<AB, 256, 0, stream>>>(hbf, rowptr, csr, aggbf);
    mlp_kernel<<<MB, 256, 0, stream>>>(aggbf, Wp + 2 * 16384, c1b1, Wp + 3 * 16384, c1b2, hbf);

    pool_kernel<<<N_GRAPHS, 128, 0, stream>>>(hbf, xb, pooled);
    reg_kernel<<<N_GRAPHS, 128, 0, stream>>>(pooled, rW1, rb1, rW2, rb2, out);
}

// Round 4
// 189.527 us; speedup vs baseline: 1.9808x; 1.1334x over previous
//
#include <hip/hip_runtime.h>
#include <stdint.h>

#define N_NODES 50000
#define N_EDGES 600000
#define DIM     128
#define N_GRAPHS 512
#define NB_SCAN 49            // ceil(50000/1024)

typedef __attribute__((ext_vector_type(8))) short bf16x8;
typedef __attribute__((ext_vector_type(4))) float f32x4;

__device__ __forceinline__ short f2bf(float f) {
    union { float f; uint32_t u; } c; c.f = f;
    uint32_t u = c.u;
    u += 0x7fffu + ((u >> 16) & 1u);   // round-to-nearest-even
    return (short)(u >> 16);
}
__device__ __forceinline__ float bflo(uint32_t u) {
    union { uint32_t u; float f; } c; c.u = u << 16; return c.f;
}
__device__ __forceinline__ float bfhi(uint32_t u) {
    union { uint32_t u; float f; } c; c.u = u & 0xffff0000u; return c.f;
}

__global__ void zero_kernel(uint4* __restrict__ p, int n16) {
    int i = blockIdx.x * blockDim.x + threadIdx.x;
    if (i < n16) p[i] = make_uint4(0, 0, 0, 0);
}

// ---- convert f32 rows -> bf16 (8 elems/thread) ----
__global__ void cvt_kernel(const float* __restrict__ in, ushort* __restrict__ out, int n8) {
    int i = blockIdx.x * blockDim.x + threadIdx.x;
    if (i >= n8) return;
    const float4* p = (const float4*)(in + (size_t)i * 8);
    float4 lo = p[0], hi = p[1];
    bf16x8 t;
    t[0] = f2bf(lo.x); t[1] = f2bf(lo.y); t[2] = f2bf(lo.z); t[3] = f2bf(lo.w);
    t[4] = f2bf(hi.x); t[5] = f2bf(hi.y); t[6] = f2bf(hi.z); t[7] = f2bf(hi.w);
    *(bf16x8*)(out + (size_t)i * 8) = t;
}

// ---- pack four 128x128 f32 row-major W into bf16 B-fragment order ----
__global__ void pack_w4_kernel(const float* __restrict__ W0, const float* __restrict__ W1,
                               const float* __restrict__ W2, const float* __restrict__ W3,
                               short* __restrict__ Wp) {
    int idx = blockIdx.x * blockDim.x + threadIdx.x;   // 0..8191
    if (idx >= 8192) return;
    int m = idx >> 11;
    int r = idx & 2047;
    const float* W = (m == 0) ? W0 : (m == 1) ? W1 : (m == 2) ? W2 : W3;
    int lane = r & 63;
    int ks = (r >> 6) & 3;
    int nt = r >> 8;
    int col = nt * 16 + (lane & 15);
    int k0 = ks * 32 + ((lane >> 4) << 3);
    short* dst = Wp + (size_t)idx * 8;
#pragma unroll
    for (int j = 0; j < 8; ++j) dst[j] = f2bf(W[(k0 + j) * DIM + col]);
}

__global__ void count_kernel(const int* __restrict__ ei, int* __restrict__ cnt) {
    int e = blockIdx.x * blockDim.x + threadIdx.x;
    if (e < N_EDGES) atomicAdd(&cnt[ei[N_EDGES + e]], 1);
}

// ---- hierarchical scan ----
__global__ void blocksum_kernel(const int* __restrict__ cnt, int* __restrict__ partial) {
    __shared__ int s[1024];
    int i = blockIdx.x * 1024 + threadIdx.x;
    s[threadIdx.x] = (i < N_NODES) ? cnt[i] : 0;
    __syncthreads();
#pragma unroll
    for (int off = 512; off; off >>= 1) {
        if (threadIdx.x < off) s[threadIdx.x] += s[threadIdx.x + off];
        __syncthreads();
    }
    if (threadIdx.x == 0) partial[blockIdx.x] = s[0];
}

__global__ void scanpartial_kernel(const int* __restrict__ partial, int* __restrict__ pbase) {
    __shared__ int s[64];
    int t = threadIdx.x;
    s[t] = (t < NB_SCAN) ? partial[t] : 0;
    __syncthreads();
#pragma unroll
    for (int off = 1; off < 64; off <<= 1) {
        int v = (t >= off) ? s[t - off] : 0;
        __syncthreads();
        s[t] += v;
        __syncthreads();
    }
    if (t < NB_SCAN) pbase[t] = (t == 0) ? 0 : s[t - 1];
}

__global__ void rowptr_kernel(const int* __restrict__ cnt, const int* __restrict__ pbase,
                              int* __restrict__ rowptr) {
    __shared__ int s[1024];
    int b = blockIdx.x, t = threadIdx.x;
    int i = b * 1024 + t;
    s[t] = (i < N_NODES) ? cnt[i] : 0;
    __syncthreads();
#pragma unroll
    for (int off = 1; off < 1024; off <<= 1) {
        int v = (t >= off) ? s[t - off] : 0;
        __syncthreads();
        s[t] += v;
        __syncthreads();
    }
    if (i < N_NODES) rowptr[i + 1] = pbase[b] + s[t];
    if (i == 0) rowptr[0] = 0;
}

__global__ void fill_kernel(const int* __restrict__ ei, const int* __restrict__ rowptr,
                            int* __restrict__ cursor, int* __restrict__ csr_src) {
    int e = blockIdx.x * blockDim.x + threadIdx.x;
    if (e < N_EDGES) {
        int dst = ei[N_EDGES + e];
        int p = atomicAdd(&cursor[dst], 1);
        csr_src[rowptr[dst] + p] = ei[e];
    }
}

// one wave per node; 4 lane-groups of 16 process 4 edges concurrently, 16B/lane
__global__ __launch_bounds__(256) void agg_kernel(const ushort* __restrict__ h,
                                                  const int* __restrict__ rowptr,
                                                  const int* __restrict__ csr_src,
                                                  ushort* __restrict__ agg) {
    int w = (blockIdx.x * 256 + threadIdx.x) >> 6;
    int lane = threadIdx.x & 63;
    if (w >= N_NODES) return;
    const int l15 = lane & 15;
    const int lg = lane >> 4;
    const uint4* h4 = (const uint4*)h;      // 16 segments of 16B per row

    float a0=0,a1=0,a2=0,a3=0,a4=0,a5=0,a6=0,a7=0;
    if (lg == 0) {                          // self-loop in group 0
        uint4 v = h4[(size_t)w * 16 + l15];
        a0 = bflo(v.x); a1 = bfhi(v.x); a2 = bflo(v.y); a3 = bfhi(v.y);
        a4 = bflo(v.z); a5 = bfhi(v.z); a6 = bflo(v.w); a7 = bfhi(v.w);
    }

    const int s = rowptr[w];
    const int e = rowptr[w + 1];
    int i = s + lg;
    for (; i + 4 < e; i += 8) {
        int idx0 = csr_src[i];
        int idx1 = csr_src[i + 4];
        uint4 v0 = h4[(size_t)idx0 * 16 + l15];
        uint4 v1 = h4[(size_t)idx1 * 16 + l15];
        a0 += bflo(v0.x); a1 += bfhi(v0.x); a2 += bflo(v0.y); a3 += bfhi(v0.y);
        a4 += bflo(v0.z); a5 += bfhi(v0.z); a6 += bflo(v0.w); a7 += bfhi(v0.w);
        a0 += bflo(v1.x); a1 += bfhi(v1.x); a2 += bflo(v1.y); a3 += bfhi(v1.y);
        a4 += bflo(v1.z); a5 += bfhi(v1.z); a6 += bflo(v1.w); a7 += bfhi(v1.w);
    }
    if (i < e) {
        int idx0 = csr_src[i];
        uint4 v0 = h4[(size_t)idx0 * 16 + l15];
        a0 += bflo(v0.x); a1 += bfhi(v0.x); a2 += bflo(v0.y); a3 += bfhi(v0.y);
        a4 += bflo(v0.z); a5 += bfhi(v0.z); a6 += bflo(v0.w); a7 += bfhi(v0.w);
    }

#pragma unroll
    for (int m = 16; m <= 32; m <<= 1) {
        a0 += __shfl_xor(a0, m); a1 += __shfl_xor(a1, m);
        a2 += __shfl_xor(a2, m); a3 += __shfl_xor(a3, m);
        a4 += __shfl_xor(a4, m); a5 += __shfl_xor(a5, m);
        a6 += __shfl_xor(a6, m); a7 += __shfl_xor(a7, m);
    }

    if (lg == 0) {
        uint4 r;
        r.x = (uint32_t)(uint16_t)f2bf(a0) | ((uint32_t)(uint16_t)f2bf(a1) << 16);
        r.y = (uint32_t)(uint16_t)f2bf(a2) | ((uint32_t)(uint16_t)f2bf(a3) << 16);
        r.z = (uint32_t)(uint16_t)f2bf(a4) | ((uint32_t)(uint16_t)f2bf(a5) << 16);
        r.w = (uint32_t)(uint16_t)f2bf(a6) | ((uint32_t)(uint16_t)f2bf(a7) << 16);
        ((uint4*)agg)[(size_t)w * 16 + l15] = r;
    }
}

// h_out = relu(A @ W1 + b1) @ W2 + b2 ; bf16 in, bf16 out; 4 waves/block, 16 nodes/wave
__global__ __launch_bounds__(256) void mlp_kernel(const ushort* __restrict__ A,
                                                  const short* __restrict__ W1p,
                                                  const float* __restrict__ b1,
                                                  const short* __restrict__ W2p,
                                                  const float* __restrict__ b2,
                                                  ushort* __restrict__ Hout) {
    __shared__ short tbuf[4][16 * 144];
    const int tid = threadIdx.x;
    const int wid = tid >> 6;
    const int lane = tid & 63;
    const int l15 = lane & 15;
    const int lg = lane >> 4;              // 0..3
    const int node0 = blockIdx.x * 64 + wid * 16;

    int arow = node0 + l15;
    if (arow >= N_NODES) arow = N_NODES - 1;
    const short* ap = (const short*)A + (size_t)arow * DIM + lg * 8;
    bf16x8 afr[4];
#pragma unroll
    for (int ks = 0; ks < 4; ++ks) afr[ks] = *(const bf16x8*)(ap + ks * 32);

    short* tb = tbuf[wid];
#pragma unroll
    for (int nt = 0; nt < 8; ++nt) {
        f32x4 acc = {0.f, 0.f, 0.f, 0.f};
#pragma unroll
        for (int ks = 0; ks < 4; ++ks) {
            bf16x8 b = *(const bf16x8*)(W1p + (size_t)(((nt * 4 + ks) << 6) + lane) * 8);
            acc = __builtin_amdgcn_mfma_f32_16x16x32_bf16(afr[ks], b, acc, 0, 0, 0);
        }
        float bias = b1[nt * 16 + l15];
#pragma unroll
        for (int i = 0; i < 4; ++i) {
            int r = lg * 4 + i;
            float v = fmaxf(acc[i] + bias, 0.f);
            tb[r * 144 + nt * 16 + l15] = f2bf(v);
        }
    }
    __syncthreads();

    bf16x8 a2[4];
#pragma unroll
    for (int ks = 0; ks < 4; ++ks)
        a2[ks] = *(const bf16x8*)(tb + l15 * 144 + ks * 32 + lg * 8);
    __syncthreads();

#pragma unroll
    for (int nt = 0; nt < 8; ++nt) {
        f32x4 acc = {0.f, 0.f, 0.f, 0.f};
#pragma unroll
        for (int ks = 0; ks < 4; ++ks) {
            bf16x8 b = *(const bf16x8*)(W2p + (size_t)(((nt * 4 + ks) << 6) + lane) * 8);
            acc = __builtin_amdgcn_mfma_f32_16x16x32_bf16(a2[ks], b, acc, 0, 0, 0);
        }
        float bias = b2[nt * 16 + l15];
#pragma unroll
        for (int i = 0; i < 4; ++i) {
            int r = lg * 4 + i;
            tb[r * 144 + nt * 16 + l15] = f2bf(acc[i] + bias);
        }
    }
    __syncthreads();

#pragma unroll
    for (int it = 0; it < 4; ++it) {
        int chunk = it * 64 + lane;
        int row = chunk >> 4;
        int seg = chunk & 15;
        bf16x8 v = *(const bf16x8*)(tb + row * 144 + seg * 8);
        int node = node0 + row;
        if (node < N_NODES) *(bf16x8*)((short*)Hout + (size_t)node * DIM + seg * 8) = v;
    }
}

// one block (128 threads = 8 groups of 16) per graph; uint4 loads; LDS reduce
__global__ __launch_bounds__(128) void pool_kernel(const ushort* __restrict__ h,
                                                   const int* __restrict__ xb,
                                                   float* __restrict__ pooled) {
    __shared__ float red[8][128];
    int g = blockIdx.x;
    int t = threadIdx.x;
    int grp = t >> 4;     // 0..7
    int l15 = t & 15;

    int lo = 0, hi = N_NODES;
    while (lo < hi) { int m = (lo + hi) >> 1; if (xb[m] < g) lo = m + 1; else hi = m; }
    int s = lo;
    hi = N_NODES;
    while (lo < hi) { int m = (lo + hi) >> 1; if (xb[m] < g + 1) lo = m + 1; else hi = m; }
    int e = lo;

    const uint4* h4 = (const uint4*)h;
    float a0=0,a1=0,a2=0,a3=0,a4=0,a5=0,a6=0,a7=0;
    for (int i = s + grp; i < e; i += 8) {
        uint4 v = h4[(size_t)i * 16 + l15];
        a0 += bflo(v.x); a1 += bfhi(v.x); a2 += bflo(v.y); a3 += bfhi(v.y);
        a4 += bflo(v.z); a5 += bfhi(v.z); a6 += bflo(v.w); a7 += bfhi(v.w);
    }
    float* rp = &red[grp][l15 * 8];
    rp[0]=a0; rp[1]=a1; rp[2]=a2; rp[3]=a3; rp[4]=a4; rp[5]=a5; rp[6]=a6; rp[7]=a7;
    __syncthreads();

    float acc = 0.f;
#pragma unroll
    for (int k = 0; k < 8; ++k) acc += red[k][t];
    float c = (e - s) > 0 ? (float)(e - s) : 1.0f;
    pooled[g * DIM + t] = acc / c;
}

__global__ void reg_kernel(const float* __restrict__ pooled, const float* __restrict__ W1,
                           const float* __restrict__ b1, const float* __restrict__ W2,
                           const float* __restrict__ b2, float* __restrict__ out) {
    __shared__ float p[128];
    __shared__ float red[128];
    int g = blockIdx.x, t = threadIdx.x;
    p[t] = pooled[g * DIM + t];
    __syncthreads();
    float acc = b1[t];
#pragma unroll 8
    for (int k = 0; k < DIM; ++k) acc = fmaf(p[k], W1[k * DIM + t], acc);
    float r = fmaxf(acc, 0.f);
    red[t] = r * W2[t];
    __syncthreads();
    for (int off = 64; off; off >>= 1) {
        if (t < off) red[t] += red[t + off];
        __syncthreads();
    }
    if (t == 0) out[g] = red[0] + b2[0];
}

extern "C" void kernel_launch(void* const* d_in, const int* in_sizes, int n_in,
                              void* d_out, int out_size, void* d_ws, size_t ws_size,
                              hipStream_t stream) {
    (void)in_sizes; (void)n_in; (void)out_size; (void)ws_size;
    const float* x     = (const float*)d_in[0];
    const int*   ei    = (const int*)d_in[1];
    const int*   xb    = (const int*)d_in[3];
    const float* c0W1  = (const float*)d_in[4];
    const float* c0b1  = (const float*)d_in[5];
    const float* c0W2  = (const float*)d_in[6];
    const float* c0b2  = (const float*)d_in[7];
    const float* c1W1  = (const float*)d_in[8];
    const float* c1b1  = (const float*)d_in[9];
    const float* c1W2  = (const float*)d_in[10];
    const float* c1b2  = (const float*)d_in[11];
    const float* rW1   = (const float*)d_in[12];
    const float* rb1   = (const float*)d_in[13];
    const float* rW2   = (const float*)d_in[14];
    const float* rb2   = (const float*)d_in[15];
    float* out = (float*)d_out;

    char* ws = (char*)d_ws;
    size_t off = 0;
    auto alloc = [&](size_t bytes) -> char* {
        char* p = ws + off;
        off = (off + bytes + 511) & ~(size_t)511;
        return p;
    };
    int*    zeros  = (int*)alloc((size_t)2 * N_NODES * 4);      // cnt | cursor
    int*    cnt    = zeros;
    int*    cursor = zeros + N_NODES;
    int*    rowptr = (int*)alloc((size_t)(N_NODES + 1) * 4);
    int*    csr    = (int*)alloc((size_t)N_EDGES * 4);
    int*    partial= (int*)alloc((size_t)64 * 4);
    int*    pbase  = (int*)alloc((size_t)64 * 4);
    ushort* xbf    = (ushort*)alloc((size_t)N_NODES * DIM * 2);
    ushort* aggbf  = (ushort*)alloc((size_t)N_NODES * DIM * 2);
    ushort* hbf    = (ushort*)alloc((size_t)N_NODES * DIM * 2);
    float*  pooled = (float*)alloc((size_t)N_GRAPHS * DIM * 4);
    short*  Wp     = (short*)alloc((size_t)4 * DIM * DIM * 2);

    const int nz16 = (2 * N_NODES * 4) / 16;   // 25000 uint4
    zero_kernel<<<(nz16 + 255) / 256, 256, 0, stream>>>((uint4*)zeros, nz16);

    pack_w4_kernel<<<32, 256, 0, stream>>>(c0W1, c0W2, c1W1, c1W2, Wp);
    const int n8 = N_NODES * DIM / 8;
    cvt_kernel<<<(n8 + 255) / 256, 256, 0, stream>>>(x, xbf, n8);

    const int EB = (N_EDGES + 255) / 256;
    count_kernel<<<EB, 256, 0, stream>>>(ei, cnt);
    blocksum_kernel<<<NB_SCAN, 1024, 0, stream>>>(cnt, partial);
    scanpartial_kernel<<<1, 64, 0, stream>>>(partial, pbase);
    rowptr_kernel<<<NB_SCAN, 1024, 0, stream>>>(cnt, pbase, rowptr);
    fill_kernel<<<EB, 256, 0, stream>>>(ei, rowptr, cursor, csr);

    const int AB = (N_NODES + 3) / 4;     // 4 nodes (waves) per block
    const int MB = (N_NODES + 63) / 64;   // 64 nodes per block

    agg_kernel<<<AB, 256, 0, stream>>>(xbf, rowptr, csr, aggbf);
    mlp_kernel<<<MB, 256, 0, stream>>>(aggbf, Wp + 0 * 16384, c0b1, Wp + 1 * 16384, c0b2, hbf);
    agg_kernel<<<AB, 256, 0, stream>>>(hbf, rowptr, csr, aggbf);
    mlp_kernel<<<MB, 256, 0, stream>>>(aggbf, Wp + 2 * 16384, c1b1, Wp + 3 * 16384, c1b2, hbf);

    pool_kernel<<<N_GRAPHS, 128, 0, stream>>>(hbf, xb, pooled);
    reg_kernel<<<N_GRAPHS, 128, 0, stream>>>(pooled, rW1, rb1, rW2, rb2, out);
}

// Round 5
// 165.212 us; speedup vs baseline: 2.2724x; 1.1472x over previous
//
#include <hip/hip_runtime.h>
#include <stdint.h>

#define N_NODES 50000
#define N_EDGES 600000
#define DIM     128
#define N_GRAPHS 512
#define NB_SCAN 49            // ceil(50000/1024)

typedef __attribute__((ext_vector_type(8))) short bf16x8;
typedef __attribute__((ext_vector_type(4))) float f32x4;

__device__ __forceinline__ short f2bf(float f) {
    union { float f; uint32_t u; } c; c.f = f;
    uint32_t u = c.u;
    u += 0x7fffu + ((u >> 16) & 1u);   // round-to-nearest-even
    return (short)(u >> 16);
}
__device__ __forceinline__ float bflo(uint32_t u) {
    union { uint32_t u; float f; } c; c.u = u << 16; return c.f;
}
__device__ __forceinline__ float bfhi(uint32_t u) {
    union { uint32_t u; float f; } c; c.u = u & 0xffff0000u; return c.f;
}

#define N8_CVT (N_NODES * DIM / 8)        // 800000
#define NZ16   (2 * N_NODES * 4 / 16)     // 25000
#define NPACK  8192

// fused: x->bf16 cvt | zero cnt/cursor | pack 4 weight matrices
__global__ void prep_kernel(const float* __restrict__ x, ushort* __restrict__ xbf,
                            uint4* __restrict__ zeros16,
                            const float* __restrict__ W0, const float* __restrict__ W1,
                            const float* __restrict__ W2, const float* __restrict__ W3,
                            short* __restrict__ Wp) {
    int idx = blockIdx.x * blockDim.x + threadIdx.x;
    if (idx < N8_CVT) {
        const float4* p = (const float4*)(x + (size_t)idx * 8);
        float4 lo = p[0], hi = p[1];
        bf16x8 t;
        t[0] = f2bf(lo.x); t[1] = f2bf(lo.y); t[2] = f2bf(lo.z); t[3] = f2bf(lo.w);
        t[4] = f2bf(hi.x); t[5] = f2bf(hi.y); t[6] = f2bf(hi.z); t[7] = f2bf(hi.w);
        *(bf16x8*)(xbf + (size_t)idx * 8) = t;
        return;
    }
    int z = idx - N8_CVT;
    if (z < NZ16) { zeros16[z] = make_uint4(0, 0, 0, 0); return; }
    int pk = z - NZ16;
    if (pk < NPACK) {
        int m = pk >> 11;
        int r = pk & 2047;
        const float* W = (m == 0) ? W0 : (m == 1) ? W1 : (m == 2) ? W2 : W3;
        int lane = r & 63;
        int ks = (r >> 6) & 3;
        int nt = r >> 8;
        int col = nt * 16 + (lane & 15);
        int k0 = ks * 32 + ((lane >> 4) << 3);
        short* dst = Wp + (size_t)pk * 8;
#pragma unroll
        for (int j = 0; j < 8; ++j) dst[j] = f2bf(W[(k0 + j) * DIM + col]);
    }
}

__global__ void count_kernel(const int* __restrict__ ei, int* __restrict__ cnt) {
    int e = blockIdx.x * blockDim.x + threadIdx.x;
    if (e < N_EDGES) atomicAdd(&cnt[ei[N_EDGES + e]], 1);
}

// ---- hierarchical scan ----
__global__ void blocksum_kernel(const int* __restrict__ cnt, int* __restrict__ partial) {
    __shared__ int s[1024];
    int i = blockIdx.x * 1024 + threadIdx.x;
    s[threadIdx.x] = (i < N_NODES) ? cnt[i] : 0;
    __syncthreads();
#pragma unroll
    for (int off = 512; off; off >>= 1) {
        if (threadIdx.x < off) s[threadIdx.x] += s[threadIdx.x + off];
        __syncthreads();
    }
    if (threadIdx.x == 0) partial[blockIdx.x] = s[0];
}

__global__ void scanpartial_kernel(const int* __restrict__ partial, int* __restrict__ pbase) {
    __shared__ int s[64];
    int t = threadIdx.x;
    s[t] = (t < NB_SCAN) ? partial[t] : 0;
    __syncthreads();
#pragma unroll
    for (int off = 1; off < 64; off <<= 1) {
        int v = (t >= off) ? s[t - off] : 0;
        __syncthreads();
        s[t] += v;
        __syncthreads();
    }
    if (t < NB_SCAN) pbase[t] = (t == 0) ? 0 : s[t - 1];
}

__global__ void rowptr_kernel(const int* __restrict__ cnt, const int* __restrict__ pbase,
                              int* __restrict__ rowptr) {
    __shared__ int s[1024];
    int b = blockIdx.x, t = threadIdx.x;
    int i = b * 1024 + t;
    s[t] = (i < N_NODES) ? cnt[i] : 0;
    __syncthreads();
#pragma unroll
    for (int off = 1; off < 1024; off <<= 1) {
        int v = (t >= off) ? s[t - off] : 0;
        __syncthreads();
        s[t] += v;
        __syncthreads();
    }
    if (i < N_NODES) rowptr[i + 1] = pbase[b] + s[t];
    if (i == 0) rowptr[0] = 0;
}

__global__ void fill_kernel(const int* __restrict__ ei, const int* __restrict__ rowptr,
                            int* __restrict__ cursor, int* __restrict__ csr_src) {
    int e = blockIdx.x * blockDim.x + threadIdx.x;
    if (e < N_EDGES) {
        int dst = ei[N_EDGES + e];
        int p = atomicAdd(&cursor[dst], 1);
        csr_src[rowptr[dst] + p] = ei[e];
    }
}

// one 16-lane group per node (16 lanes x 16B = full 256B row), 4 nodes/wave,
// edge loop unrolled x4 -> up to 16 row-loads in flight per wave, no shuffles
__global__ __launch_bounds__(256) void agg_kernel(const ushort* __restrict__ h,
                                                  const int* __restrict__ rowptr,
                                                  const int* __restrict__ csr_src,
                                                  ushort* __restrict__ agg) {
    int node = (blockIdx.x * 256 + threadIdx.x) >> 4;
    if (node >= N_NODES) return;
    int l15 = threadIdx.x & 15;
    const uint4* h4 = (const uint4*)h;

    uint4 v = h4[(size_t)node * 16 + l15];    // self-loop
    float a0 = bflo(v.x), a1 = bfhi(v.x), a2 = bflo(v.y), a3 = bfhi(v.y);
    float a4 = bflo(v.z), a5 = bfhi(v.z), a6 = bflo(v.w), a7 = bfhi(v.w);

    const int s = rowptr[node];
    const int e = rowptr[node + 1];
    int i = s;
    for (; i + 3 < e; i += 4) {
        int i0 = csr_src[i], i1 = csr_src[i + 1], i2 = csr_src[i + 2], i3 = csr_src[i + 3];
        uint4 v0 = h4[(size_t)i0 * 16 + l15];
        uint4 v1 = h4[(size_t)i1 * 16 + l15];
        uint4 v2 = h4[(size_t)i2 * 16 + l15];
        uint4 v3 = h4[(size_t)i3 * 16 + l15];
        a0 += bflo(v0.x); a1 += bfhi(v0.x); a2 += bflo(v0.y); a3 += bfhi(v0.y);
        a4 += bflo(v0.z); a5 += bfhi(v0.z); a6 += bflo(v0.w); a7 += bfhi(v0.w);
        a0 += bflo(v1.x); a1 += bfhi(v1.x); a2 += bflo(v1.y); a3 += bfhi(v1.y);
        a4 += bflo(v1.z); a5 += bfhi(v1.z); a6 += bflo(v1.w); a7 += bfhi(v1.w);
        a0 += bflo(v2.x); a1 += bfhi(v2.x); a2 += bflo(v2.y); a3 += bfhi(v2.y);
        a4 += bflo(v2.z); a5 += bfhi(v2.z); a6 += bflo(v2.w); a7 += bfhi(v2.w);
        a0 += bflo(v3.x); a1 += bfhi(v3.x); a2 += bflo(v3.y); a3 += bfhi(v3.y);
        a4 += bflo(v3.z); a5 += bfhi(v3.z); a6 += bflo(v3.w); a7 += bfhi(v3.w);
    }
    for (; i < e; ++i) {
        uint4 v0 = h4[(size_t)csr_src[i] * 16 + l15];
        a0 += bflo(v0.x); a1 += bfhi(v0.x); a2 += bflo(v0.y); a3 += bfhi(v0.y);
        a4 += bflo(v0.z); a5 += bfhi(v0.z); a6 += bflo(v0.w); a7 += bfhi(v0.w);
    }

    uint4 r;
    r.x = (uint32_t)(uint16_t)f2bf(a0) | ((uint32_t)(uint16_t)f2bf(a1) << 16);
    r.y = (uint32_t)(uint16_t)f2bf(a2) | ((uint32_t)(uint16_t)f2bf(a3) << 16);
    r.z = (uint32_t)(uint16_t)f2bf(a4) | ((uint32_t)(uint16_t)f2bf(a5) << 16);
    r.w = (uint32_t)(uint16_t)f2bf(a6) | ((uint32_t)(uint16_t)f2bf(a7) << 16);
    ((uint4*)agg)[(size_t)node * 16 + l15] = r;
}

// h_out = relu(A @ W1 + b1) @ W2 + b2 ; 32 nodes/wave (B-fragment reused for 2 MFMAs),
// 2 waves/block (64 nodes/block)
__global__ __launch_bounds__(128) void mlp_kernel(const ushort* __restrict__ A,
                                                  const short* __restrict__ W1p,
                                                  const float* __restrict__ b1,
                                                  const short* __restrict__ W2p,
                                                  const float* __restrict__ b2,
                                                  ushort* __restrict__ Hout) {
    __shared__ short tbuf[2][32 * 144];
    const int tid = threadIdx.x;
    const int wid = tid >> 6;              // 0..1
    const int lane = tid & 63;
    const int l15 = lane & 15;
    const int lg = lane >> 4;              // 0..3
    const int node0 = blockIdx.x * 64 + wid * 32;

    int rowA = node0 + l15;      if (rowA >= N_NODES) rowA = N_NODES - 1;
    int rowB = node0 + 16 + l15; if (rowB >= N_NODES) rowB = N_NODES - 1;
    const short* apA = (const short*)A + (size_t)rowA * DIM + lg * 8;
    const short* apB = (const short*)A + (size_t)rowB * DIM + lg * 8;
    bf16x8 afrA[4], afrB[4];
#pragma unroll
    for (int ks = 0; ks < 4; ++ks) {
        afrA[ks] = *(const bf16x8*)(apA + ks * 32);
        afrB[ks] = *(const bf16x8*)(apB + ks * 32);
    }

    short* tb = tbuf[wid];
#pragma unroll
    for (int nt = 0; nt < 8; ++nt) {
        f32x4 accA = {0.f, 0.f, 0.f, 0.f};
        f32x4 accB = {0.f, 0.f, 0.f, 0.f};
#pragma unroll
        for (int ks = 0; ks < 4; ++ks) {
            bf16x8 b = *(const bf16x8*)(W1p + (size_t)(((nt * 4 + ks) << 6) + lane) * 8);
            accA = __builtin_amdgcn_mfma_f32_16x16x32_bf16(afrA[ks], b, accA, 0, 0, 0);
            accB = __builtin_amdgcn_mfma_f32_16x16x32_bf16(afrB[ks], b, accB, 0, 0, 0);
        }
        float bias = b1[nt * 16 + l15];
#pragma unroll
        for (int i = 0; i < 4; ++i) {
            int r = lg * 4 + i;
            tb[r * 144 + nt * 16 + l15] = f2bf(fmaxf(accA[i] + bias, 0.f));
            tb[(r + 16) * 144 + nt * 16 + l15] = f2bf(fmaxf(accB[i] + bias, 0.f));
        }
    }
    __syncthreads();

    bf16x8 a2A[4], a2B[4];
#pragma unroll
    for (int ks = 0; ks < 4; ++ks) {
        a2A[ks] = *(const bf16x8*)(tb + l15 * 144 + ks * 32 + lg * 8);
        a2B[ks] = *(const bf16x8*)(tb + (16 + l15) * 144 + ks * 32 + lg * 8);
    }
    __syncthreads();

#pragma unroll
    for (int nt = 0; nt < 8; ++nt) {
        f32x4 accA = {0.f, 0.f, 0.f, 0.f};
        f32x4 accB = {0.f, 0.f, 0.f, 0.f};
#pragma unroll
        for (int ks = 0; ks < 4; ++ks) {
            bf16x8 b = *(const bf16x8*)(W2p + (size_t)(((nt * 4 + ks) << 6) + lane) * 8);
            accA = __builtin_amdgcn_mfma_f32_16x16x32_bf16(a2A[ks], b, accA, 0, 0, 0);
            accB = __builtin_amdgcn_mfma_f32_16x16x32_bf16(a2B[ks], b, accB, 0, 0, 0);
        }
        float bias = b2[nt * 16 + l15];
#pragma unroll
        for (int i = 0; i < 4; ++i) {
            int r = lg * 4 + i;
            tb[r * 144 + nt * 16 + l15] = f2bf(accA[i] + bias);
            tb[(r + 16) * 144 + nt * 16 + l15] = f2bf(accB[i] + bias);
        }
    }
    __syncthreads();

    // write 32 rows x 128 bf16: 8 iterations x 64 lanes x 16B
#pragma unroll
    for (int it = 0; it < 8; ++it) {
        int chunk = it * 64 + lane;    // 0..511
        int row = chunk >> 4;          // 0..31
        int seg = chunk & 15;
        bf16x8 v = *(const bf16x8*)(tb + row * 144 + seg * 8);
        int node = node0 + row;
        if (node < N_NODES) *(bf16x8*)((short*)Hout + (size_t)node * DIM + seg * 8) = v;
    }
}

// fused mean-pool + regressor MLP: one block (128 threads) per graph
__global__ __launch_bounds__(128) void poolreg_kernel(const ushort* __restrict__ h,
                                                      const int* __restrict__ xb,
                                                      const float* __restrict__ W1,
                                                      const float* __restrict__ b1,
                                                      const float* __restrict__ W2,
                                                      const float* __restrict__ b2,
                                                      float* __restrict__ out) {
    __shared__ float red[8][128];
    __shared__ float p[128];
    int g = blockIdx.x;
    int t = threadIdx.x;
    int grp = t >> 4;     // 0..7
    int l15 = t & 15;

    int lo = 0, hi = N_NODES;
    while (lo < hi) { int m = (lo + hi) >> 1; if (xb[m] < g) lo = m + 1; else hi = m; }
    int s = lo;
    hi = N_NODES;
    while (lo < hi) { int m = (lo + hi) >> 1; if (xb[m] < g + 1) lo = m + 1; else hi = m; }
    int e = lo;

    const uint4* h4 = (const uint4*)h;
    float a0=0,a1=0,a2=0,a3=0,a4=0,a5=0,a6=0,a7=0;
    for (int i = s + grp; i < e; i += 8) {
        uint4 v = h4[(size_t)i * 16 + l15];
        a0 += bflo(v.x); a1 += bfhi(v.x); a2 += bflo(v.y); a3 += bfhi(v.y);
        a4 += bflo(v.z); a5 += bfhi(v.z); a6 += bflo(v.w); a7 += bfhi(v.w);
    }
    float* rp = &red[grp][l15 * 8];
    rp[0]=a0; rp[1]=a1; rp[2]=a2; rp[3]=a3; rp[4]=a4; rp[5]=a5; rp[6]=a6; rp[7]=a7;
    __syncthreads();

    float acc = 0.f;
#pragma unroll
    for (int k = 0; k < 8; ++k) acc += red[k][t];
    float c = (e - s) > 0 ? (float)(e - s) : 1.0f;
    p[t] = acc / c;
    __syncthreads();

    // regressor: relu(p @ W1 + b1) @ W2 + b2
    float acc2 = b1[t];
#pragma unroll 8
    for (int k = 0; k < DIM; ++k) acc2 = fmaf(p[k], W1[k * DIM + t], acc2);
    float r = fmaxf(acc2, 0.f);
    float* rd = &red[0][0];
    rd[t] = r * W2[t];
    __syncthreads();
    for (int off = 64; off; off >>= 1) {
        if (t < off) rd[t] += rd[t + off];
        __syncthreads();
    }
    if (t == 0) out[g] = rd[0] + b2[0];
}

extern "C" void kernel_launch(void* const* d_in, const int* in_sizes, int n_in,
                              void* d_out, int out_size, void* d_ws, size_t ws_size,
                              hipStream_t stream) {
    (void)in_sizes; (void)n_in; (void)out_size; (void)ws_size;
    const float* x     = (const float*)d_in[0];
    const int*   ei    = (const int*)d_in[1];
    const int*   xb    = (const int*)d_in[3];
    const float* c0W1  = (const float*)d_in[4];
    const float* c0b1  = (const float*)d_in[5];
    const float* c0W2  = (const float*)d_in[6];
    const float* c0b2  = (const float*)d_in[7];
    const float* c1W1  = (const float*)d_in[8];
    const float* c1b1  = (const float*)d_in[9];
    const float* c1W2  = (const float*)d_in[10];
    const float* c1b2  = (const float*)d_in[11];
    const float* rW1   = (const float*)d_in[12];
    const float* rb1   = (const float*)d_in[13];
    const float* rW2   = (const float*)d_in[14];
    const float* rb2   = (const float*)d_in[15];
    float* out = (float*)d_out;

    char* ws = (char*)d_ws;
    size_t off = 0;
    auto alloc = [&](size_t bytes) -> char* {
        char* p = ws + off;
        off = (off + bytes + 511) & ~(size_t)511;
        return p;
    };
    int*    zeros  = (int*)alloc((size_t)2 * N_NODES * 4);      // cnt | cursor
    int*    cnt    = zeros;
    int*    cursor = zeros + N_NODES;
    int*    rowptr = (int*)alloc((size_t)(N_NODES + 1) * 4);
    int*    csr    = (int*)alloc((size_t)N_EDGES * 4);
    int*    partial= (int*)alloc((size_t)64 * 4);
    int*    pbase  = (int*)alloc((size_t)64 * 4);
    ushort* xbf    = (ushort*)alloc((size_t)N_NODES * DIM * 2);
    ushort* aggbf  = (ushort*)alloc((size_t)N_NODES * DIM * 2);
    ushort* hbf    = (ushort*)alloc((size_t)N_NODES * DIM * 2);
    short*  Wp     = (short*)alloc((size_t)4 * DIM * DIM * 2);

    // fused prep: cvt x -> bf16 | zero cnt/cursor | pack weights
    const int PREP_TOTAL = N8_CVT + NZ16 + NPACK;
    prep_kernel<<<(PREP_TOTAL + 255) / 256, 256, 0, stream>>>(
        x, xbf, (uint4*)zeros, c0W1, c0W2, c1W1, c1W2, Wp);

    const int EB = (N_EDGES + 255) / 256;
    count_kernel<<<EB, 256, 0, stream>>>(ei, cnt);
    blocksum_kernel<<<NB_SCAN, 1024, 0, stream>>>(cnt, partial);
    scanpartial_kernel<<<1, 64, 0, stream>>>(partial, pbase);
    rowptr_kernel<<<NB_SCAN, 1024, 0, stream>>>(cnt, pbase, rowptr);
    fill_kernel<<<EB, 256, 0, stream>>>(ei, rowptr, cursor, csr);

    const int AB = (N_NODES * 16 + 255) / 256;   // 16 lanes per node
    const int MB = (N_NODES + 63) / 64;          // 64 nodes per block (2 waves)

    agg_kernel<<<AB, 256, 0, stream>>>(xbf, rowptr, csr, aggbf);
    mlp_kernel<<<MB, 128, 0, stream>>>(aggbf, Wp + 0 * 16384, c0b1, Wp + 1 * 16384, c0b2, hbf);
    agg_kernel<<<AB, 256, 0, stream>>>(hbf, rowptr, csr, aggbf);
    mlp_kernel<<<MB, 128, 0, stream>>>(aggbf, Wp + 2 * 16384, c1b1, Wp + 3 * 16384, c1b2, hbf);

    poolreg_kernel<<<N_GRAPHS, 128, 0, stream>>>(hbf, xb, rW1, rb1, rW2, rb2, out);
}